// Round 3
// baseline (173.901 us; speedup 1.0000x reference)
//
#include <hip/hip_runtime.h>

// RoiPooling: crop + bilinear 7x7 resize, TF1 resize_bilinear (align_corners=False).
// feat: (128,128,1024) fp32, rois: (512,4) fp32 [ymin,xmin,ymax,xmax], out: (512,7,7,1024) fp32.
//
// R5 restructure (R4 was neutral: nt-store/thrash theory wrong; kernel is
// request-path/latency bound at 3.6 TB/s while fillBuffer hits 6.5 TB/s):
//  - One block per (ROI, py): 7 output cells share the two source rows gy0/gy1.
//    Rolling 2-column register cache deduplicates taps across px: stage px
//    reuses columns held from px-1 (x0(px)==x1(px-1) etc.) and loads only
//    missing columns. Per-px dead-tap: fx==0 or x-clip -> right column dead;
//    ny==false (fy==0 or y-clip) -> entire second row dead (res = top, exact).
//    All reuse/skip decisions are block-uniform -> zero divergence.
//    Cuts L1/L2 read-request traffic ~1.5-2x (196 taps/ROI -> ~unique pixels).
//  - 3584 blocks x 256 threads (vs 25088 x 128): 7x work per block, less churn,
//    28KB contiguous nt-stores per block.
//  - XCD swizzle kept: all 7 blocks of a ROI share blockIdx%8 (one XCD's L2).
//
// Exactness argument (bit-exact vs reference):
//  - Reused registers hold the SAME memory values the reference would load
//    (colA/colB track which column each register actually holds).
//  - needR==false cases: either x1==x0 (tr IS tl in ref) or fx==0 (tr weight
//    exactly 0.0f; finite values -> (tr-tl)*0 == 0). Both give top==tl exactly.
//  - ny==false: either y1==y0 (bot computed from identical values -> bot==top)
//    or fy==0 -> out = top exactly.

#define POOL_P 7
#define FEAT_C 1024
#define FEAT_W 128
#define GROUP_BLOCKS (8 * POOL_P)   // 56: 8 ROIs x 7 row-pairs

typedef float vfloat4 __attribute__((ext_vector_type(4)));

__global__ __launch_bounds__(256) void roi_pool_kernel(
    const float* __restrict__ feat,
    const float* __restrict__ rois,
    float* __restrict__ out)
{
    // ---- XCD swizzle: blockIdx%8 is (heuristically) the XCD; keep it fixed per ROI.
    const int i  = blockIdx.x;
    const int q  = i / GROUP_BLOCKS;          // ROI group of 8
    const int k  = i - q * GROUP_BLOCKS;      // [0,56)
    const int r  = 8 * q + (k & 7);           // ROI id (k%8 fixed per ROI)
    const int py = k >> 3;                    // [0,7)

    // ---- ROI box (block-uniform scalar math)
    const float4 roi = ((const float4*)rois)[r];
    const int ymin = (int)roi.x;
    const int xmin = (int)roi.y;
    const int ymax = (int)roi.z;
    const int xmax = (int)roi.w;

    const float h = (float)(ymax - ymin + 1);
    const float w = (float)(xmax - xmin + 1);

    // NB: exact reference rounding: src = py * (h / 7.0f)
    const float src_y = (float)py * (h / 7.0f);
    const int y0 = (int)floorf(src_y);
    const int y1 = min(y0 + 1, ymax - ymin);
    const float fy = src_y - (float)y0;
    const bool ny = (y1 != y0) && (fy != 0.0f);

    const float* __restrict__ row0 = feat + (size_t)((ymin + y0) * FEAT_W) * FEAT_C;
    const float* __restrict__ row1 = feat + (size_t)((ymin + y1) * FEAT_W) * FEAT_C;

    const int t = threadIdx.x;                // float4 index in channel dim [0,256)

    // out rows for (r, py, px=0..6)
    vfloat4* __restrict__ op = (vfloat4*)(out + ((size_t)r * 49 + (size_t)py * 7) * FEAT_C);

    // ---- column schedule (block-uniform, fully unrolled -> registers)
    int X0[POOL_P], X1[POOL_P];
    float FX[POOL_P];
    const float wstep = w / 7.0f;
    #pragma unroll
    for (int px = 0; px < POOL_P; ++px) {
        const float sx = (float)px * wstep;
        const int x0 = (int)floorf(sx);
        X0[px] = x0;
        X1[px] = min(x0 + 1, xmax - xmin);
        FX[px] = sx - (float)x0;
    }

    // ---- rolling 2-column register cache
    float4 tl, tr, bl, br;        // held values: col colA -> (tl,bl), colB -> (tr,br)
    int colA = -1, colB = -1;     // feature columns (ROI-local) actually held

    #pragma unroll
    for (int px = 0; px < POOL_P; ++px) {
        const int cL = X0[px];
        const int cR = X1[px];
        const bool needR = (cR != cL) && (FX[px] != 0.0f);

        float4 ntl, ntr, nbl, nbr;

        // left column (cL >= colA always; may equal colA or colB)
        if (cL == colA)      { ntl = tl; nbl = bl; }
        else if (cL == colB) { ntl = tr; nbl = br; }
        else {
            const float* p0 = row0 + (size_t)(xmin + cL) * FEAT_C;
            ntl = ((const float4*)p0)[t];
            if (ny) {
                const float* p1 = row1 + (size_t)(xmin + cL) * FEAT_C;
                nbl = ((const float4*)p1)[t];
            } else nbl = ntl;     // defined but dead (DCE'd)
        }

        // right column (cR == cL+1 when needed; can only match old colB)
        if (!needR)          { ntr = ntl; nbr = nbl; }
        else if (cR == colB) { ntr = tr; nbr = br; }
        else {
            const float* p0 = row0 + (size_t)(xmin + cR) * FEAT_C;
            ntr = ((const float4*)p0)[t];
            if (ny) {
                const float* p1 = row1 + (size_t)(xmin + cR) * FEAT_C;
                nbr = ((const float4*)p1)[t];
            } else nbr = ntr;     // defined but dead
        }

        tl = ntl; tr = ntr; bl = nbl; br = nbr;
        colA = cL;
        colB = needR ? cR : cL;

        // ---- bilinear blend (exact reference formula; ny==false -> res = top exactly)
        const float fxv = FX[px];
        vfloat4 res;
        {
            float top;
            top = tl.x + (tr.x - tl.x) * fxv;
            res.x = ny ? top + ((bl.x + (br.x - bl.x) * fxv) - top) * fy : top;
            top = tl.y + (tr.y - tl.y) * fxv;
            res.y = ny ? top + ((bl.y + (br.y - bl.y) * fxv) - top) * fy : top;
            top = tl.z + (tr.z - tl.z) * fxv;
            res.z = ny ? top + ((bl.z + (br.z - bl.z) * fxv) - top) * fy : top;
            top = tl.w + (tr.w - tl.w) * fxv;
            res.w = ny ? top + ((bl.w + (br.w - bl.w) * fxv) - top) * fy : top;
        }

        // write-once output: keep it out of the caches
        __builtin_nontemporal_store(res, &op[(size_t)px * 256 + t]);
    }
}

extern "C" void kernel_launch(void* const* d_in, const int* in_sizes, int n_in,
                              void* d_out, int out_size, void* d_ws, size_t ws_size,
                              hipStream_t stream) {
    const float* feat = (const float*)d_in[0];   // (1,128,128,1024) fp32
    const float* rois = (const float*)d_in[1];   // (512,4) fp32
    float* out        = (float*)d_out;           // (512, 7*7*1024) fp32

    const int n_rois   = in_sizes[1] / 4;        // 512
    const int n_blocks = n_rois * POOL_P;        // 3584

    roi_pool_kernel<<<n_blocks, 256, 0, stream>>>(feat, rois, out);
}

// Round 5
// 168.542 us; speedup vs baseline: 1.0318x; 1.0318x over previous
//
#include <hip/hip_runtime.h>

// RoiPooling: crop + bilinear 7x7 resize, TF1 resize_bilinear (align_corners=False).
// feat: (128,128,1024) fp32, rois: (512,4) fp32 [ymin,xmin,ymax,xmax], out: (512,7,7,1024) fp32.
//
// R7 = R6 resubmitted (previous bench died on container infra, not the kernel).
//  - roi_sort_kernel: 1-block bitonic sort of 512 ROI indices by (ymin,xmin),
//    permutation written to d_ws. ~2us.
//  - Main kernel maps its ROI *slot* through the permutation. With the XCD
//    swizzle, each XCD sweeps the map top-to-bottom processing spatially
//    adjacent ROIs back-to-back (consecutive ROIs on one XCD differ by ~2 in
//    ymin, footprints overlap ~90%). Active read working set becomes a ~20MB
//    y-band shared by all XCDs instead of the whole 64MB map in random order
//    -> cross-ROI reads hit L2/L3 instead of re-fetching (FETCH was 1.9x map).
//  - Output address uses the REAL ROI id -> results identical; only execution
//    order changes.
//  - Keeps R4's dead-tap skipping (bit-exact) and nt stores.

#define POOL_P 7
#define FEAT_C 1024
#define FEAT_W 128
#define CELLS_PER_ROI (POOL_P * POOL_P)          // 49
#define GROUP_BLOCKS  (8 * CELLS_PER_ROI)        // 392: 8 ROIs x 49 cells
#define N_ROIS 512

typedef float vfloat4 __attribute__((ext_vector_type(4)));

// ---- 1-block bitonic sort: key = ((ymin<<7)|xmin)<<10 | idx --------------
__global__ __launch_bounds__(N_ROIS) void roi_sort_kernel(
    const float* __restrict__ rois, unsigned* __restrict__ perm)
{
    __shared__ unsigned sk[N_ROIS];
    const int tid = threadIdx.x;
    {
        const float4 roi = ((const float4*)rois)[tid];
        const unsigned ymin = (unsigned)(int)roi.x;   // [0,126]
        const unsigned xmin = (unsigned)(int)roi.y;   // [0,126]
        sk[tid] = (((ymin << 7) | xmin) << 10) | (unsigned)tid;
    }
    __syncthreads();
    for (int k = 2; k <= N_ROIS; k <<= 1) {
        for (int j = k >> 1; j > 0; j >>= 1) {
            const int ixj = tid ^ j;
            if (ixj > tid) {
                const bool up = ((tid & k) == 0);
                const unsigned a = sk[tid], b = sk[ixj];
                if ((a > b) == up) { sk[tid] = b; sk[ixj] = a; }
            }
            __syncthreads();
        }
    }
    perm[tid] = sk[tid] & 1023u;
}

// ---- main kernel (R4 body + slot->roi permutation) -----------------------
__global__ __launch_bounds__(128) void roi_pool_kernel(
    const float* __restrict__ feat,
    const float* __restrict__ rois,
    float* __restrict__ out,
    const unsigned* __restrict__ perm)
{
    // XCD swizzle: blockIdx%8 is (heuristically) the XCD; fixed per ROI slot.
    const int i     = blockIdx.x;
    const int q     = i / GROUP_BLOCKS;          // slot group of 8
    const int k     = i - q * GROUP_BLOCKS;      // [0,392)
    const int rslot = 8 * q + (k & 7);           // sorted-order slot
    const int cell  = k >> 3;                    // [0,49)
    const int px    = cell % POOL_P;
    const int py    = cell / POOL_P;

    // Map slot -> real ROI id via spatial sort (uniform scalar load).
    const int r = perm ? (int)perm[rslot] : rslot;

    // ---- ROI box (block-uniform scalar math)
    const float4 roi = ((const float4*)rois)[r];
    const int ymin = (int)roi.x;
    const int xmin = (int)roi.y;
    const int ymax = (int)roi.z;
    const int xmax = (int)roi.w;

    const float h = (float)(ymax - ymin + 1);
    const float w = (float)(xmax - xmin + 1);

    // NB: exact reference rounding: src = py * (h / 7.0f)
    const float src_y = (float)py * (h / 7.0f);
    const float src_x = (float)px * (w / 7.0f);

    const int y0 = (int)floorf(src_y);
    const int x0 = (int)floorf(src_x);
    const int y1 = min(y0 + 1, ymax - ymin);
    const int x1 = min(x0 + 1, xmax - xmin);

    const float fy = src_y - (float)y0;
    const float fx = src_x - (float)x0;

    // Dead-tap analysis (uniform across the block) — bit-exact substitutions:
    //  !nx: fx==0 (tr weight exactly 0) or x1==x0 (tr IS tl) -> skip tr.
    //  !ny: fy==0 or y1==y0 -> skip bl. br needs both.
    const bool nx = (x1 != x0) && (fx != 0.0f);
    const bool ny = (y1 != y0) && (fy != 0.0f);

    const int gy0 = ymin + y0;
    const int gy1 = ymin + y1;
    const int gx0 = xmin + x0;
    const int gx1 = xmin + x1;

    const float4* __restrict__ tlp = (const float4*)(feat + ((size_t)(gy0 * FEAT_W + gx0)) * FEAT_C);
    const float4* __restrict__ trp = (const float4*)(feat + ((size_t)(gy0 * FEAT_W + gx1)) * FEAT_C);
    const float4* __restrict__ blp = (const float4*)(feat + ((size_t)(gy1 * FEAT_W + gx0)) * FEAT_C);
    const float4* __restrict__ brp = (const float4*)(feat + ((size_t)(gy1 * FEAT_W + gx1)) * FEAT_C);
    vfloat4* __restrict__ op = (vfloat4*)(out + ((size_t)r * CELLS_PER_ROI + cell) * FEAT_C);

    const int t0 = threadIdx.x;                  // [0,128)
    const int t1 = t0 + 128;

    // Issue all live loads before any use (max outstanding vmcnt).
    const float4 tl0 = tlp[t0];
    const float4 tl1 = tlp[t1];
    float4 tr0, tr1, bl0, bl1, br0, br1;
    if (nx)       { tr0 = trp[t0]; tr1 = trp[t1]; }
    if (ny)       { bl0 = blp[t0]; bl1 = blp[t1]; }
    if (nx && ny) { br0 = brp[t0]; br1 = brp[t1]; }

    // Exact fallbacks for skipped taps.
    if (!nx) { tr0 = tl0; tr1 = tl1; }
    if (!ny) { bl0 = tl0; bl1 = tl1; }
    if (!(nx && ny)) {
        br0 = (!nx) ? bl0 : tr0;    // !nx: br:=bl (bot=bl exactly); !ny: br:=tr (bot=top)
        br1 = (!nx) ? bl1 : tr1;
    }

    vfloat4 res0, res1;
    {
        float top, bot;
        top = tl0.x + (tr0.x - tl0.x) * fx; bot = bl0.x + (br0.x - bl0.x) * fx; res0.x = top + (bot - top) * fy;
        top = tl0.y + (tr0.y - tl0.y) * fx; bot = bl0.y + (br0.y - bl0.y) * fx; res0.y = top + (bot - top) * fy;
        top = tl0.z + (tr0.z - tl0.z) * fx; bot = bl0.z + (br0.z - bl0.z) * fx; res0.z = top + (bot - top) * fy;
        top = tl0.w + (tr0.w - tl0.w) * fx; bot = bl0.w + (br0.w - bl0.w) * fx; res0.w = top + (bot - top) * fy;
        top = tl1.x + (tr1.x - tl1.x) * fx; bot = bl1.x + (br1.x - bl1.x) * fx; res1.x = top + (bot - top) * fy;
        top = tl1.y + (tr1.y - tl1.y) * fx; bot = bl1.y + (br1.y - bl1.y) * fx; res1.y = top + (bot - top) * fy;
        top = tl1.z + (tr1.z - tl1.z) * fx; bot = bl1.z + (br1.z - bl1.z) * fx; res1.z = top + (bot - top) * fy;
        top = tl1.w + (tr1.w - tl1.w) * fx; bot = bl1.w + (br1.w - bl1.w) * fx; res1.w = top + (bot - top) * fy;
    }

    // Write-once output: keep it out of the caches.
    __builtin_nontemporal_store(res0, &op[t0]);
    __builtin_nontemporal_store(res1, &op[t1]);
}

extern "C" void kernel_launch(void* const* d_in, const int* in_sizes, int n_in,
                              void* d_out, int out_size, void* d_ws, size_t ws_size,
                              hipStream_t stream) {
    const float* feat = (const float*)d_in[0];   // (1,128,128,1024) fp32
    const float* rois = (const float*)d_in[1];   // (512,4) fp32
    float* out        = (float*)d_out;           // (512, 7*7*1024) fp32

    const int n_rois   = in_sizes[1] / 4;              // 512
    const int n_blocks = n_rois * CELLS_PER_ROI;       // 25088

    unsigned* perm = nullptr;
    if (n_rois == N_ROIS && ws_size >= N_ROIS * sizeof(unsigned)) {
        perm = (unsigned*)d_ws;
        roi_sort_kernel<<<1, N_ROIS, 0, stream>>>(rois, perm);
    }
    roi_pool_kernel<<<n_blocks, 128, 0, stream>>>(feat, rois, out, perm);
}